// Round 2
// baseline (973.631 us; speedup 1.0000x reference)
//
#include <hip/hip_runtime.h>
#include <math.h>

#define NIMG 16
#define CCH  256
#define HW_  4096
#define NP_  65536
#define EPS_ 1e-12f

// ---------------- reduction helpers (blockDim.x == 256) ----------------
__device__ __forceinline__ float block_sum(float v, volatile float* sc){
  #pragma unroll
  for(int o=32;o>0;o>>=1) v += __shfl_down(v,o,64);
  __syncthreads();
  if((threadIdx.x&63)==0) sc[threadIdx.x>>6]=v;
  __syncthreads();
  return sc[0]+sc[1]+sc[2]+sc[3];
}
__device__ __forceinline__ float block_min(float v, volatile float* sc){
  #pragma unroll
  for(int o=32;o>0;o>>=1) v = fminf(v,__shfl_down(v,o,64));
  __syncthreads();
  if((threadIdx.x&63)==0) sc[threadIdx.x>>6]=v;
  __syncthreads();
  return fminf(fminf(sc[0],sc[1]),fminf(sc[2],sc[3]));
}
__device__ __forceinline__ float block_max(float v, volatile float* sc){
  #pragma unroll
  for(int o=32;o>0;o>>=1) v = fmaxf(v,__shfl_down(v,o,64));
  __syncthreads();
  if((threadIdx.x&63)==0) sc[threadIdx.x>>6]=v;
  __syncthreads();
  return fmaxf(fmaxf(sc[0],sc[1]),fmaxf(sc[2],sc[3]));
}

// ---------------- K1: sigmoid(SISMs) and per-pixel channel inv-norm ----------------
__global__ void k_siginv(const float* __restrict__ feats, const float* __restrict__ SISMs,
                         float* __restrict__ sig, float* __restrict__ inv){
  int j = blockIdx.x*256 + threadIdx.x;        // 256 blocks -> 65536 pixels
  int n = j>>12, p = j&4095;
  const float* fb = feats + (size_t)n*CCH*HW_ + p;
  float acc = 0.f;
  #pragma unroll 8
  for(int c=0;c<CCH;c++){ float v = fb[(size_t)c*HW_]; acc = fmaf(v,v,acc); }
  inv[j] = 1.f/fmaxf(sqrtf(acc), EPS_);
  sig[j] = 1.f/(1.f+expf(-SISMs[j]));
}

// ---------------- K2: weighted[b][n][c] = mean_p NFs*sis ----------------
__global__ void k_weighted(const float* __restrict__ feats, const float* __restrict__ sig,
                           const float* __restrict__ inv, float* __restrict__ wt){
  int nc = blockIdx.x;                 // n*256+c
  int n = nc>>8;
  const float* row = feats + (size_t)nc*HW_;
  const float* sg = sig + (size_t)n*HW_;
  const float* iv = inv + (size_t)n*HW_;
  float af=0.f, ab=0.f;
  for(int p=threadIdx.x;p<HW_;p+=256){
    float v = row[p]*iv[p];
    float s = sg[p];
    af = fmaf(v,s,af);
    ab = fmaf(v,1.f-s,ab);
  }
  __shared__ float sc4[4];
  float tf = block_sum(af, sc4);
  float tb = block_sum(ab, sc4);
  if(threadIdx.x==0){
    wt[nc]        = tf*(1.f/4096.f);
    wt[4096+nc]   = tb*(1.f/4096.f);
  }
}

// ---------------- K3: co_proxy (per-n l2norm) and r_co_proxy ----------------
__global__ void k_proxy(const float* __restrict__ wt, float* __restrict__ cp, float* __restrict__ rc){
  int c = threadIdx.x;
  __shared__ float sc4[4];
  for(int b=0;b<2;b++){
    const float* w = wt + (size_t)b*4096;
    float wv[16];
    #pragma unroll
    for(int n=0;n<16;n++) wv[n] = w[n*256+c];
    for(int n=0;n<16;n++){
      float ss = block_sum(wv[n]*wv[n], sc4);
      float rinv = 1.f/fmaxf(sqrtf(ss), EPS_);
      cp[(size_t)b*4096 + n*256 + c] = wv[n]*rinv;
    }
    float mean = 0.f;
    #pragma unroll
    for(int n=0;n<16;n++) mean += wv[n];
    mean *= (1.f/16.f);
    float ss = block_sum(mean*mean, sc4);
    rc[(size_t)b*256 + c] = mean/fmaxf(sqrtf(ss), EPS_);
  }
}

// ---------------- K4: corr[b][n][m][p] (unnormalized*inv) and scores ----------------
__global__ void k_corr(const float* __restrict__ feats, const float* __restrict__ inv,
                       const float* __restrict__ cp, const float* __restrict__ rc,
                       float* __restrict__ corr, float* __restrict__ score){
  __shared__ float s_cp[2*16*256];
  __shared__ float s_rc[2*256];
  int tid = threadIdx.x;
  for(int i=tid;i<2*16*256;i+=256) s_cp[i] = cp[i];
  for(int i=tid;i<512;i+=256) s_rc[i] = rc[i];
  __syncthreads();
  int j = blockIdx.x*256 + tid;
  int n = j>>12, p = j&4095;
  const float* fb = feats + (size_t)n*CCH*HW_ + p;
  float af[16], ab[16], sf=0.f, sb=0.f;
  #pragma unroll
  for(int m=0;m<16;m++){ af[m]=0.f; ab[m]=0.f; }
  for(int c=0;c<CCH;c++){
    float v = fb[(size_t)c*HW_];
    #pragma unroll
    for(int m=0;m<16;m++){
      af[m] = fmaf(v, s_cp[m*256+c],          af[m]);
      ab[m] = fmaf(v, s_cp[4096 + m*256+c],   ab[m]);
    }
    sf = fmaf(v, s_rc[c],     sf);
    sb = fmaf(v, s_rc[256+c], sb);
  }
  float iv = inv[j];
  #pragma unroll
  for(int m=0;m<16;m++){
    corr[((size_t)(n*16+m))*HW_ + p]            = af[m]*iv;
    corr[(size_t)1048576 + ((size_t)(n*16+m))*HW_ + p] = ab[m]*iv;
  }
  score[j]       = sf*iv;
  score[NP_+j]   = sb*iv;
}

// ---------------- K5: att = minmax-normalized sum_m l2norm(corr) ----------------
__global__ void k_att(const float* __restrict__ corr, float* __restrict__ att){
  int n = blockIdx.x, b = blockIdx.y;
  const float* cb = corr + ((size_t)b*256 + n*16)*HW_;
  __shared__ float sc4[4];
  __shared__ float rinv[16];
  __shared__ float buf[4096];
  int tid = threadIdx.x;
  for(int m=0;m<16;m++){
    float l=0.f;
    for(int i=tid;i<HW_;i+=256){ float x = cb[(size_t)m*HW_+i]; l = fmaf(x,x,l); }
    float t = block_sum(l, sc4);
    if(tid==0) rinv[m] = 1.f/fmaxf(sqrtf(t), EPS_);
  }
  __syncthreads();
  float mn= __builtin_inff(), mx=-__builtin_inff();
  for(int i=tid;i<HW_;i+=256){
    float a=0.f;
    #pragma unroll
    for(int m=0;m<16;m++) a = fmaf(cb[(size_t)m*HW_+i], rinv[m], a);
    buf[i]=a; mn=fminf(mn,a); mx=fmaxf(mx,a);
  }
  float gmn = block_min(mn, sc4);
  float gmx = block_max(mx, sc4);
  for(int i=tid;i<HW_;i+=256)
    att[(size_t)b*NP_ + n*HW_ + i] = (buf[i]-gmn)/(gmx-gmn+EPS_);
}

// ---------------- K6: top-32 stage 1 (per 1024-chunk local top-32) ----------------
__global__ void k_top1(const float* __restrict__ score, float* __restrict__ cval, int* __restrict__ cidx){
  const int b = blockIdx.y;
  const int base = blockIdx.x*1024;
  __shared__ float v[1024];
  __shared__ float redv[4]; __shared__ int redp[4];
  const int tid = threadIdx.x;
  const float* s = score + (size_t)b*NP_;
  for(int i=tid;i<1024;i+=256) v[i] = s[base+i];
  __syncthreads();
  for(int k=0;k<32;k++){
    float bv=-__builtin_inff(); int bp=1<<30;
    for(int i=tid;i<1024;i+=256){
      float x=v[i];
      if(x>bv){ bv=x; bp=i; }       // ascending i: strict > keeps smallest index on tie
    }
    #pragma unroll
    for(int o=32;o>0;o>>=1){
      float ov=__shfl_down(bv,o,64); int op=__shfl_down(bp,o,64);
      if(ov>bv || (ov==bv && op<bp)){ bv=ov; bp=op; }
    }
    if((tid&63)==0){ redv[tid>>6]=bv; redp[tid>>6]=bp; }
    __syncthreads();
    if(tid==0){
      float fv=redv[0]; int fp=redp[0];
      for(int w=1;w<4;w++) if(redv[w]>fv || (redv[w]==fv && redp[w]<fp)){ fv=redv[w]; fp=redp[w]; }
      cval[((size_t)b*64 + blockIdx.x)*32 + k] = fv;
      cidx[((size_t)b*64 + blockIdx.x)*32 + k] = base + fp;
      v[fp] = -__builtin_inff();
    }
    __syncthreads();
  }
}

// ---------------- K7: top-32 stage 2 (merge 2048 candidates) + gather co_rep ----------------
__global__ void k_top2(const float* __restrict__ cval, const int* __restrict__ cidx,
                       const float* __restrict__ feats, const float* __restrict__ inv,
                       float* __restrict__ crep){
  const int b = blockIdx.x;
  __shared__ float v[2048]; __shared__ int gj[2048];
  __shared__ float redv[4]; __shared__ int redp[4]; __shared__ int redj[4];
  __shared__ int topj[32];
  const int tid = threadIdx.x;
  for(int i=tid;i<2048;i+=256){ v[i]=cval[(size_t)b*2048+i]; gj[i]=cidx[(size_t)b*2048+i]; }
  __syncthreads();
  for(int k=0;k<32;k++){
    float bv=-__builtin_inff(); int bp=1<<30; int bj=0x7fffffff;
    for(int i=tid;i<2048;i+=256){
      float x=v[i]; int j=gj[i];
      if(x>bv || (x==bv && j<bj)){ bv=x; bp=i; bj=j; }
    }
    #pragma unroll
    for(int o=32;o>0;o>>=1){
      float ov=__shfl_down(bv,o,64); int op=__shfl_down(bp,o,64); int oj=__shfl_down(bj,o,64);
      if(ov>bv || (ov==bv && oj<bj)){ bv=ov; bp=op; bj=oj; }
    }
    if((tid&63)==0){ redv[tid>>6]=bv; redp[tid>>6]=bp; redj[tid>>6]=bj; }
    __syncthreads();
    if(tid==0){
      float fv=redv[0]; int fp=redp[0]; int fj=redj[0];
      for(int w=1;w<4;w++) if(redv[w]>fv || (redv[w]==fv && redj[w]<fj)){ fv=redv[w]; fp=redp[w]; fj=redj[w]; }
      topj[k]=fj; v[fp] = -__builtin_inff();
    }
    __syncthreads();
  }
  // gather co_rep[k][c] = NFs[n_k, c, p_k]
  for(int k=0;k<32;k++){
    int j = topj[k]; int n = j>>12, p = j&4095;
    float ivn = inv[j];
    crep[(size_t)b*8192 + k*256 + tid] = feats[((size_t)(n*CCH)+tid)*HW_ + p]*ivn;
  }
}

// ---------------- K8: M[b][o][c] = sum_k w_sub[o][k]*co_rep[b][k][c] ----------------
__global__ void k_M(const float* __restrict__ w_sub, const float* __restrict__ crep,
                    float* __restrict__ M){
  int b = blockIdx.y, o = blockIdx.x, c = threadIdx.x;
  __shared__ float wr[32];
  __shared__ float cr[32*256];
  if(c<32) wr[c] = w_sub[o*32+c];
  for(int i=c;i<8192;i+=256) cr[i] = crep[(size_t)b*8192+i];
  __syncthreads();
  float a=0.f;
  #pragma unroll
  for(int k=0;k<32;k++) a = fmaf(wr[k], cr[k*256+c], a);
  M[(size_t)b*65536 + o*256 + c] = a;
}

// ---------------- K9: fore/back = att*inv*(M@feats) + b_sub  (written to d_out) ----------------
__global__ __launch_bounds__(256) void k_fb(const float* __restrict__ feats,
    const float* __restrict__ Mm, const float* __restrict__ att,
    const float* __restrict__ inv, const float* __restrict__ b_sub,
    float* __restrict__ dout){
  __shared__ float sA0[16][68];
  __shared__ float sA1[16][68];
  __shared__ float sX [16][68];
  const int tid = threadIdx.x;
  const int o0 = blockIdx.x*64;
  const int j0 = blockIdx.y*64;
  const int n = j0>>12, p0 = j0&4095;
  const int tx = tid&15, ty = tid>>4;
  const int ao = tid>>2, ak = (tid&3)*4;
  const int xk = tid>>4, xp = (tid&15)*4;
  float accf[4][4], accb[4][4];
  #pragma unroll
  for(int r=0;r<4;r++){
    #pragma unroll
    for(int q=0;q<4;q++){ accf[r][q]=0.f; accb[r][q]=0.f; }
  }
  const float* Xb = feats + (size_t)n*CCH*HW_ + p0;
  for(int c0=0;c0<CCH;c0+=16){
    float4 a0 = *(const float4*)&Mm[(size_t)(o0+ao)*CCH + c0 + ak];
    float4 a1 = *(const float4*)&Mm[(size_t)CCH*CCH + (size_t)(o0+ao)*CCH + c0 + ak];
    float4 xv = *(const float4*)&Xb[(size_t)(c0+xk)*HW_ + xp];
    __syncthreads();
    sA0[ak+0][ao]=a0.x; sA0[ak+1][ao]=a0.y; sA0[ak+2][ao]=a0.z; sA0[ak+3][ao]=a0.w;
    sA1[ak+0][ao]=a1.x; sA1[ak+1][ao]=a1.y; sA1[ak+2][ao]=a1.z; sA1[ak+3][ao]=a1.w;
    *(float4*)&sX[xk][xp] = xv;
    __syncthreads();
    #pragma unroll
    for(int k=0;k<16;k++){
      float4 xr = *(const float4*)&sX [k][tx*4];
      float4 fr = *(const float4*)&sA0[k][ty*4];
      float4 br = *(const float4*)&sA1[k][ty*4];
      float xa[4]={xr.x,xr.y,xr.z,xr.w};
      float fa[4]={fr.x,fr.y,fr.z,fr.w};
      float ba[4]={br.x,br.y,br.z,br.w};
      #pragma unroll
      for(int r=0;r<4;r++){
        #pragma unroll
        for(int q=0;q<4;q++){
          accf[r][q]=fmaf(fa[r],xa[q],accf[r][q]);
          accb[r][q]=fmaf(ba[r],xa[q],accb[r][q]);
        }
      }
    }
  }
  const int jp = j0 + tx*4;
  float sf[4], sb[4];
  #pragma unroll
  for(int q=0;q<4;q++){
    float iv = inv[jp+q];
    sf[q] = att[jp+q]*iv;
    sb[q] = att[NP_+jp+q]*iv;
  }
  const size_t OF = (size_t)NIMG*CCH*HW_;
  #pragma unroll
  for(int r=0;r<4;r++){
    int o = o0 + ty*4 + r;
    float bs = b_sub[o];
    float4 vf, vb;
    vf.x=fmaf(accf[r][0],sf[0],bs); vf.y=fmaf(accf[r][1],sf[1],bs);
    vf.z=fmaf(accf[r][2],sf[2],bs); vf.w=fmaf(accf[r][3],sf[3],bs);
    vb.x=fmaf(accb[r][0],sb[0],bs); vb.y=fmaf(accb[r][1],sb[1],bs);
    vb.z=fmaf(accb[r][2],sb[2],bs); vb.w=fmaf(accb[r][3],sb[3],bs);
    size_t op = ((size_t)(n*CCH+o))*HW_ + p0 + tx*4;
    *(float4*)&dout[OF   + op] = vf;
    *(float4*)&dout[2*OF + op] = vb;
  }
}

// ---------------- K10: enhanced = w_out @ [fore;back] + b_out ----------------
__global__ __launch_bounds__(256) void k_out(const float* __restrict__ w_out,
    const float* __restrict__ b_out, float* __restrict__ dout){
  __shared__ float sA[16][68];
  __shared__ float sX[16][68];
  const int tid = threadIdx.x;
  const int o0 = blockIdx.x*64;
  const int j0 = blockIdx.y*64;
  const int n = j0>>12, p0 = j0&4095;
  const int tx = tid&15, ty = tid>>4;
  const int ao = tid>>2, ak = (tid&3)*4;
  const int xk = tid>>4, xp = (tid&15)*4;
  float acc[4][4];
  #pragma unroll
  for(int r=0;r<4;r++){
    #pragma unroll
    for(int q=0;q<4;q++) acc[r][q]=0.f;
  }
  const size_t OF = (size_t)NIMG*CCH*HW_;
  for(int c0=0;c0<2*CCH;c0+=16){
    float4 a0 = *(const float4*)&w_out[(size_t)(o0+ao)*(2*CCH) + c0 + ak];
    int c = c0 + xk;
    const float* Xs = (c<CCH) ? (dout + OF   + ((size_t)(n*CCH+c))*HW_     + p0 + xp)
                              : (dout + 2*OF + ((size_t)(n*CCH+c-CCH))*HW_ + p0 + xp);
    float4 xv = *(const float4*)Xs;
    __syncthreads();
    sA[ak+0][ao]=a0.x; sA[ak+1][ao]=a0.y; sA[ak+2][ao]=a0.z; sA[ak+3][ao]=a0.w;
    *(float4*)&sX[xk][xp] = xv;
    __syncthreads();
    #pragma unroll
    for(int k=0;k<16;k++){
      float4 xr = *(const float4*)&sX[k][tx*4];
      float4 ar = *(const float4*)&sA[k][ty*4];
      float xa[4]={xr.x,xr.y,xr.z,xr.w};
      float aa[4]={ar.x,ar.y,ar.z,ar.w};
      #pragma unroll
      for(int r=0;r<4;r++){
        #pragma unroll
        for(int q=0;q<4;q++) acc[r][q]=fmaf(aa[r],xa[q],acc[r][q]);
      }
    }
  }
  #pragma unroll
  for(int r=0;r<4;r++){
    int o = o0 + ty*4 + r;
    float bs = b_out[o];
    float4 ve;
    ve.x=acc[r][0]+bs; ve.y=acc[r][1]+bs; ve.z=acc[r][2]+bs; ve.w=acc[r][3]+bs;
    *(float4*)&dout[((size_t)(n*CCH+o))*HW_ + p0 + tx*4] = ve;
  }
}

extern "C" void kernel_launch(void* const* d_in, const int* in_sizes, int n_in,
                              void* d_out, int out_size, void* d_ws, size_t ws_size,
                              hipStream_t stream) {
  const float* feats = (const float*)d_in[0];
  const float* SISMs = (const float*)d_in[1];
  const float* w_sub = (const float*)d_in[2];
  const float* b_sub = (const float*)d_in[3];
  const float* w_out = (const float*)d_in[4];
  const float* b_out = (const float*)d_in[5];
  float* out = (float*)d_out;
  float* ws  = (float*)d_ws;

  float* w_sig   = ws;                 // 65536
  float* w_inv   = ws + 65536;         // 65536
  float* w_wt    = ws + 131072;        // 2*4096
  float* w_cp    = ws + 139264;        // 2*4096
  float* w_rc    = ws + 147456;        // 2*256
  float* w_corr  = ws + 147968;        // 2*1048576
  float* w_score = ws + 2245120;       // 2*65536
  float* w_att   = ws + 2376192;       // 2*65536
  float* w_cval  = ws + 2507264;       // 2*2048
  int*   w_cidx  = (int*)(ws + 2511360); // 2*2048
  float* w_crep  = ws + 2515456;       // 2*8192
  float* w_M     = ws + 2531840;       // 2*65536

  k_siginv  <<<256, 256, 0, stream>>>(feats, SISMs, w_sig, w_inv);
  k_weighted<<<4096,256, 0, stream>>>(feats, w_sig, w_inv, w_wt);
  k_proxy   <<<1,   256, 0, stream>>>(w_wt, w_cp, w_rc);
  k_corr    <<<256, 256, 0, stream>>>(feats, w_inv, w_cp, w_rc, w_corr, w_score);
  k_att     <<<dim3(16,2), 256, 0, stream>>>(w_corr, w_att);
  k_top1    <<<dim3(64,2), 256, 0, stream>>>(w_score, w_cval, w_cidx);
  k_top2    <<<2,   256, 0, stream>>>(w_cval, w_cidx, feats, w_inv, w_crep);
  k_M       <<<dim3(256,2),256, 0, stream>>>(w_sub, w_crep, w_M);
  k_fb      <<<dim3(4,1024),256,0, stream>>>(feats, w_M, w_att, w_inv, b_sub, out);
  k_out     <<<dim3(4,1024),256,0, stream>>>(w_out, b_out, out);
}